// Round 1
// baseline (1910.461 us; speedup 1.0000x reference)
//
#include <hip/hip_runtime.h>

#define NN 50000
#define NE 800000

// ---------------- zero: d_out, ssum, counts ----------------
__global__ __launch_bounds__(256) void zero_all(float4* __restrict__ out4,
                                                float4* __restrict__ ssum4,
                                                int4* __restrict__ counts4) {
  const int i = blockIdx.x * 256 + threadIdx.x;   // exactly NN*128/4 = 1.6M threads
  const float4 z = {0.f, 0.f, 0.f, 0.f};
  out4[i] = z;
  ssum4[i] = z;
  if (i < NN / 4) { const int4 zi = {0, 0, 0, 0}; counts4[i] = zi; }
}

// ---------------- CSR build ----------------
__global__ __launch_bounds__(256) void count_kernel(const int* __restrict__ ei,
                                                    int* __restrict__ counts) {
  const int e = blockIdx.x * 256 + threadIdx.x;
  if (e < NE) atomicAdd(&counts[ei[NE + e]], 1);
}

// single-wave serial scan with carry (50000 / 64 = 782 iterations)
__global__ void scan_kernel(const int* __restrict__ counts,
                            int* __restrict__ rowptr, int n) {
  const int lane = threadIdx.x;  // 64 threads
  int carry = 0;
  if (lane == 0) rowptr[0] = 0;
  for (int base = 0; base < n; base += 64) {
    const int i = base + lane;
    int v = (i < n) ? counts[i] : 0;
    #pragma unroll
    for (int off = 1; off < 64; off <<= 1) {
      const int t = __shfl_up(v, off, 64);
      if (lane >= off) v += t;
    }
    v += carry;
    if (i < n) rowptr[i + 1] = v;
    carry = __shfl(v, 63, 64);
  }
}

__global__ __launch_bounds__(256) void copy_cursor(const int* __restrict__ rowptr,
                                                   int* __restrict__ cursor) {
  const int i = blockIdx.x * 256 + threadIdx.x;
  if (i < NN) cursor[i] = rowptr[i];
}

__global__ __launch_bounds__(256) void scatter_kernel(const int* __restrict__ ei,
                                                      int* __restrict__ cursor,
                                                      int* __restrict__ ssrc,
                                                      int* __restrict__ sdst) {
  const int e = blockIdx.x * 256 + threadIdx.x;
  if (e < NE) {
    const int s = ei[e], d = ei[NE + e];
    const int p = atomicAdd(&cursor[d], 1);
    ssrc[p] = s;
    sdst[p] = d;
  }
}

// ---------------- node GEMMs: h = x@Wl, as = x@Ws, ad = x@Wd ----------------
// wave task = (rowgroup of 16 rows) x (one 64-col chunk of one of 3 outputs)
__global__ __launch_bounds__(256) void gemm3_kernel(
    const float* __restrict__ x,
    const float* __restrict__ Wl, const float* __restrict__ Ws, const float* __restrict__ Wd,
    float* __restrict__ h, float* __restrict__ as_, float* __restrict__ ad_) {
  const int wtask = __builtin_amdgcn_readfirstlane((int)((blockIdx.x * 256 + threadIdx.x) >> 6));
  if (wtask >= 3125 * 6) return;
  const int lane = threadIdx.x & 63;
  const int rg = wtask / 6;
  const int chunk = wtask % 6;
  const int mat = chunk >> 1;
  const int cb = (chunk & 1) << 6;
  const float* __restrict__ W = (mat == 0) ? Wl : ((mat == 1) ? Ws : Wd);
  float* __restrict__ O = (mat == 0) ? h : ((mat == 1) ? as_ : ad_);
  const int col = cb + lane;
  const int r0 = rg * 16;
  float acc[16];
  #pragma unroll
  for (int r = 0; r < 16; ++r) acc[r] = 0.f;
  const float4* x4 = (const float4*)x;
  #pragma unroll 1
  for (int k4 = 0; k4 < 32; ++k4) {
    float4 xs[16];
    #pragma unroll
    for (int r = 0; r < 16; ++r) xs[r] = x4[(size_t)(r0 + r) * 32 + k4];  // wave-uniform -> s_load
    #pragma unroll
    for (int j = 0; j < 4; ++j) {
      const float wv = W[(size_t)(k4 * 4 + j) * 128 + col];               // coalesced
      #pragma unroll
      for (int r = 0; r < 16; ++r)
        acc[r] = fmaf(((const float*)&xs[r])[j], wv, acc[r]);
    }
  }
  #pragma unroll
  for (int r = 0; r < 16; ++r) O[(size_t)(r0 + r) * 128 + col] = acc[r];
}

// ---------------- edge kernel: lane = one edge (CSR order, dst sorted) ----------------
__global__ __launch_bounds__(256, 2) void edge_kernel(
    const int* __restrict__ ssrc, const int* __restrict__ sdst,
    const float* __restrict__ pos,
    const float* __restrict__ hbuf, const float* __restrict__ asb, const float* __restrict__ adb,
    const float* __restrict__ Wp1, const float* __restrict__ bp1,
    const float* __restrict__ Wp2, const float* __restrict__ bp2,
    const float* __restrict__ Wa1, const float* __restrict__ ba1,
    const float* __restrict__ Wa2, const float* __restrict__ ba2,
    float* __restrict__ outacc, float* __restrict__ ssum) {
  const int t = blockIdx.x * 256 + threadIdx.x;   // grid exactly covers NE
  const int lane = threadIdx.x & 63;
  const int src = ssrc[t];
  const int dst = sdst[t];

  const float2 pd = ((const float2*)pos)[dst];
  const float2 ps = ((const float2*)pos)[src];
  const float p0 = pd.x - ps.x;
  const float p1 = pd.y - ps.y;

  // segmented-scan predicates over the sorted dst runs in this wave
  bool take[6];
  #pragma unroll
  for (int i = 0; i < 6; ++i) {
    const int off = 1 << i;
    const int dd = __shfl_down(dst, off, 64);
    take[i] = (lane + off < 64) && (dd == dst);
  }
  const int dup = __shfl_up(dst, 1, 64);
  const bool head = (lane == 0) || (dup != dst);

  // pos_nn hidden: hd[k] = relu(p0*Wp1[0][k] + p1*Wp1[1][k] + bp1[k])
  float hd[64];
  #pragma unroll
  for (int k = 0; k < 64; k += 4) {
    const float4 w0 = *(const float4*)(Wp1 + k);
    const float4 w1 = *(const float4*)(Wp1 + 64 + k);
    const float4 bb = *(const float4*)(bp1 + k);
    hd[k + 0] = fmaxf(fmaf(p0, w0.x, fmaf(p1, w1.x, bb.x)), 0.f);
    hd[k + 1] = fmaxf(fmaf(p0, w0.y, fmaf(p1, w1.y, bb.y)), 0.f);
    hd[k + 2] = fmaxf(fmaf(p0, w0.z, fmaf(p1, w1.z, bb.z)), 0.f);
    hd[k + 3] = fmaxf(fmaf(p0, w0.w, fmaf(p1, w1.w, bb.w)), 0.f);
  }

  float ha[64];
  #pragma unroll
  for (int k = 0; k < 64; ++k) ha[k] = 0.f;

  const float4* ad4 = (const float4*)(adb + (size_t)dst * 128);
  const float4* as4 = (const float4*)(asb + (size_t)src * 128);

  // pass 1: delta_c -> u_c -> accumulate attn hidden ha[k]
  #pragma unroll 1
  for (int c4 = 0; c4 < 32; ++c4) {
    const float4 av = ad4[c4];
    const float4 sv = as4[c4];
    const float4 bb = *(const float4*)(bp2 + c4 * 4);
    float d0 = bb.x, d1 = bb.y, d2 = bb.z, d3 = bb.w;
    #pragma unroll
    for (int k = 0; k < 64; ++k) {
      const float4 w = *(const float4*)(Wp2 + k * 128 + c4 * 4);  // uniform -> s_load
      d0 = fmaf(hd[k], w.x, d0);
      d1 = fmaf(hd[k], w.y, d1);
      d2 = fmaf(hd[k], w.z, d2);
      d3 = fmaf(hd[k], w.w, d3);
    }
    float u[4];
    u[0] = av.x - sv.x + fmaxf(d0, 0.f);
    u[1] = av.y - sv.y + fmaxf(d1, 0.f);
    u[2] = av.z - sv.z + fmaxf(d2, 0.f);
    u[3] = av.w - sv.w + fmaxf(d3, 0.f);
    #pragma unroll
    for (int j = 0; j < 4; ++j) {
      const float uj = u[j];
      const float* wa1 = Wa1 + (size_t)(c4 * 4 + j) * 64;
      #pragma unroll
      for (int k = 0; k < 64; k += 4) {
        const float4 w = *(const float4*)(wa1 + k);
        ha[k + 0] = fmaf(uj, w.x, ha[k + 0]);
        ha[k + 1] = fmaf(uj, w.y, ha[k + 1]);
        ha[k + 2] = fmaf(uj, w.z, ha[k + 2]);
        ha[k + 3] = fmaf(uj, w.w, ha[k + 3]);
      }
    }
  }

  #pragma unroll
  for (int k = 0; k < 64; k += 4) {
    const float4 bb = *(const float4*)(ba1 + k);
    ha[k + 0] = fmaxf(ha[k + 0] + bb.x, 0.f);
    ha[k + 1] = fmaxf(ha[k + 1] + bb.y, 0.f);
    ha[k + 2] = fmaxf(ha[k + 2] + bb.z, 0.f);
    ha[k + 3] = fmaxf(ha[k + 3] + bb.w, 0.f);
  }

  const float4* h4 = (const float4*)(hbuf + (size_t)src * 128);
  float* accrow = outacc + (size_t)dst * 128;
  float* srow = ssum + (size_t)dst * 128;

  // pass 2: logits -> e=exp(l) (no max-sub: l>=0, bounded) -> weighted value, reduce, atomics
  #pragma unroll 1
  for (int c4 = 0; c4 < 32; ++c4) {
    const float4 hv = h4[c4];
    const float4 b2 = *(const float4*)(ba2 + c4 * 4);
    const float4 bp = *(const float4*)(bp2 + c4 * 4);
    float l0 = b2.x, l1 = b2.y, l2 = b2.z, l3 = b2.w;
    #pragma unroll
    for (int k = 0; k < 64; ++k) {
      const float4 wa = *(const float4*)(Wa2 + k * 128 + c4 * 4);
      l0 = fmaf(ha[k], wa.x, l0);
      l1 = fmaf(ha[k], wa.y, l1);
      l2 = fmaf(ha[k], wa.z, l2);
      l3 = fmaf(ha[k], wa.w, l3);
    }
    float e0 = bp.x, e1 = bp.y, e2 = bp.z, e3 = bp.w;  // delta recompute
    #pragma unroll
    for (int k = 0; k < 64; ++k) {
      const float4 wp = *(const float4*)(Wp2 + k * 128 + c4 * 4);
      e0 = fmaf(hd[k], wp.x, e0);
      e1 = fmaf(hd[k], wp.y, e1);
      e2 = fmaf(hd[k], wp.z, e2);
      e3 = fmaf(hd[k], wp.w, e3);
    }
    float ee[4], vv[4];
    ee[0] = __expf(fmaxf(l0, 0.f)); vv[0] = ee[0] * (hv.x + fmaxf(e0, 0.f));
    ee[1] = __expf(fmaxf(l1, 0.f)); vv[1] = ee[1] * (hv.y + fmaxf(e1, 0.f));
    ee[2] = __expf(fmaxf(l2, 0.f)); vv[2] = ee[2] * (hv.z + fmaxf(e2, 0.f));
    ee[3] = __expf(fmaxf(l3, 0.f)); vv[3] = ee[3] * (hv.w + fmaxf(e3, 0.f));

    // in-wave segmented suffix-sum over equal-dst runs
    #pragma unroll
    for (int i = 0; i < 6; ++i) {
      const int off = 1 << i;
      #pragma unroll
      for (int j = 0; j < 4; ++j) {
        const float de = __shfl_down(ee[j], off, 64);
        const float dv = __shfl_down(vv[j], off, 64);
        if (take[i]) { ee[j] += de; vv[j] += dv; }
      }
    }
    if (head) {
      #pragma unroll
      for (int j = 0; j < 4; ++j) {
        unsafeAtomicAdd(&srow[c4 * 4 + j], ee[j]);
        unsafeAtomicAdd(&accrow[c4 * 4 + j], vv[j]);
      }
    }
  }
}

// ---------------- finalize: out = relu(acc / (ssum + 1e-16)) ----------------
__global__ __launch_bounds__(256) void finalize_kernel(float4* __restrict__ out4,
                                                       const float4* __restrict__ ssum4) {
  const int i = blockIdx.x * 256 + threadIdx.x;
  const float4 v = out4[i];
  const float4 s = ssum4[i];
  float4 r;
  r.x = fmaxf(v.x / (s.x + 1e-16f), 0.f);
  r.y = fmaxf(v.y / (s.y + 1e-16f), 0.f);
  r.z = fmaxf(v.z / (s.z + 1e-16f), 0.f);
  r.w = fmaxf(v.w / (s.w + 1e-16f), 0.f);
  out4[i] = r;
}

extern "C" void kernel_launch(void* const* d_in, const int* in_sizes, int n_in,
                              void* d_out, int out_size, void* d_ws, size_t ws_size,
                              hipStream_t stream) {
  const float* x     = (const float*)d_in[0];
  const float* pos   = (const float*)d_in[1];
  const int*   ei    = (const int*)d_in[2];
  const float* W_lin = (const float*)d_in[3];
  const float* W_src = (const float*)d_in[4];
  const float* W_dst = (const float*)d_in[5];
  const float* Wp1   = (const float*)d_in[6];
  const float* bp1   = (const float*)d_in[7];
  const float* Wp2   = (const float*)d_in[8];
  const float* bp2   = (const float*)d_in[9];
  const float* Wa1   = (const float*)d_in[10];
  const float* ba1   = (const float*)d_in[11];
  const float* Wa2   = (const float*)d_in[12];
  const float* ba2   = (const float*)d_in[13];
  float* out = (float*)d_out;

  // workspace layout
  float* h    = (float*)d_ws;                      // NN*128
  float* as_  = h   + (size_t)NN * 128;            // NN*128
  float* ad_  = as_ + (size_t)NN * 128;            // NN*128
  float* ssum = ad_ + (size_t)NN * 128;            // NN*128
  int* counts = (int*)(ssum + (size_t)NN * 128);   // NN
  int* rowptr = counts + NN;                       // NN+1
  int* cursor = rowptr + NN + 1;                   // NN
  int* ssrc   = cursor + NN;                       // NE
  int* sdst   = ssrc + NE;                         // NE

  zero_all<<<6250, 256, 0, stream>>>((float4*)out, (float4*)ssum, (int4*)counts);
  count_kernel<<<3125, 256, 0, stream>>>(ei, counts);
  scan_kernel<<<1, 64, 0, stream>>>(counts, rowptr, NN);
  copy_cursor<<<196, 256, 0, stream>>>(rowptr, cursor);
  scatter_kernel<<<3125, 256, 0, stream>>>(ei, cursor, ssrc, sdst);
  gemm3_kernel<<<4688, 256, 0, stream>>>(x, W_lin, W_src, W_dst, h, as_, ad_);
  edge_kernel<<<3125, 256, 0, stream>>>(ssrc, sdst, pos, h, as_, ad_,
                                        Wp1, bp1, Wp2, bp2, Wa1, ba1, Wa2, ba2,
                                        out, ssum);
  finalize_kernel<<<6250, 256, 0, stream>>>((float4*)out, (const float4*)ssum);
}

// Round 2
// 1454.830 us; speedup vs baseline: 1.3132x; 1.3132x over previous
//
#include <hip/hip_runtime.h>

#define NN 50000
#define NE 800000

// ---------------- zero: d_out, ssum, counts ----------------
__global__ __launch_bounds__(256) void zero_all(float4* __restrict__ out4,
                                                float4* __restrict__ ssum4,
                                                int4* __restrict__ counts4) {
  const int i = blockIdx.x * 256 + threadIdx.x;   // exactly NN*128/4 = 1.6M threads
  const float4 z = {0.f, 0.f, 0.f, 0.f};
  out4[i] = z;
  ssum4[i] = z;
  if (i < NN / 4) { const int4 zi = {0, 0, 0, 0}; counts4[i] = zi; }
}

// ---------------- CSR build ----------------
__global__ __launch_bounds__(256) void count_kernel(const int* __restrict__ ei,
                                                    int* __restrict__ counts) {
  const int e = blockIdx.x * 256 + threadIdx.x;
  if (e < NE) atomicAdd(&counts[ei[NE + e]], 1);
}

// hierarchical scan, phase 1: per-block (256 elems) exclusive prefix + block sum
__global__ __launch_bounds__(256) void scan_block(const int* __restrict__ counts,
                                                  int* __restrict__ ep,
                                                  int* __restrict__ blocksum) {
  const int i = blockIdx.x * 256 + threadIdx.x;
  const int lane = threadIdx.x & 63;
  const int w = threadIdx.x >> 6;
  const int v = (i < NN) ? counts[i] : 0;
  int s = v;
  #pragma unroll
  for (int off = 1; off < 64; off <<= 1) {
    const int t = __shfl_up(s, off, 64);
    if (lane >= off) s += t;
  }
  __shared__ int wsums[4];
  if (lane == 63) wsums[w] = s;
  __syncthreads();
  int add = 0;
  for (int j = 0; j < w; ++j) add += wsums[j];
  s += add;
  if (i < NN) ep[i] = s - v;  // exclusive within block
  if (threadIdx.x == 255) blocksum[blockIdx.x] = s;
}

// phase 2: single-wave scan of 196 block sums -> exclusive block offsets
__global__ void scan_tops(const int* __restrict__ blocksum,
                          int* __restrict__ blockoff, int n) {
  const int lane = threadIdx.x;  // 64 threads
  int carry = 0;
  for (int base = 0; base < n; base += 64) {
    const int i = base + lane;
    const int v = (i < n) ? blocksum[i] : 0;
    int s = v;
    #pragma unroll
    for (int off = 1; off < 64; off <<= 1) {
      const int t = __shfl_up(s, off, 64);
      if (lane >= off) s += t;
    }
    s += carry;
    if (i < n) blockoff[i] = s - v;  // exclusive
    carry = __shfl(s, 63, 64);
  }
}

// phase 3: cursor[i] = global exclusive prefix (CSR row start)
__global__ __launch_bounds__(256) void scan_finish(const int* __restrict__ ep,
                                                   const int* __restrict__ blockoff,
                                                   int* __restrict__ cursor) {
  const int i = blockIdx.x * 256 + threadIdx.x;
  if (i < NN) cursor[i] = ep[i] + blockoff[blockIdx.x];
}

__global__ __launch_bounds__(256) void scatter_kernel(const int* __restrict__ ei,
                                                      int* __restrict__ cursor,
                                                      int* __restrict__ ssrc,
                                                      int* __restrict__ sdst) {
  const int e = blockIdx.x * 256 + threadIdx.x;
  if (e < NE) {
    const int s = ei[e], d = ei[NE + e];
    const int p = atomicAdd(&cursor[d], 1);
    ssrc[p] = s;
    sdst[p] = d;
  }
}

// ---------------- node GEMMs: h = x@Wl, as = x@Ws, ad = x@Wd ----------------
// wave task = (rowgroup of 16 rows) x (one 64-col chunk of one of 3 outputs)
__global__ __launch_bounds__(256) void gemm3_kernel(
    const float* __restrict__ x,
    const float* __restrict__ Wl, const float* __restrict__ Ws, const float* __restrict__ Wd,
    float* __restrict__ h, float* __restrict__ as_, float* __restrict__ ad_) {
  const int wtask = __builtin_amdgcn_readfirstlane((int)((blockIdx.x * 256 + threadIdx.x) >> 6));
  if (wtask >= 3125 * 6) return;
  const int lane = threadIdx.x & 63;
  const int rg = wtask / 6;
  const int chunk = wtask % 6;
  const int mat = chunk >> 1;
  const int cb = (chunk & 1) << 6;
  const float* __restrict__ W = (mat == 0) ? Wl : ((mat == 1) ? Ws : Wd);
  float* __restrict__ O = (mat == 0) ? h : ((mat == 1) ? as_ : ad_);
  const int col = cb + lane;
  const int r0 = rg * 16;
  float acc[16];
  #pragma unroll
  for (int r = 0; r < 16; ++r) acc[r] = 0.f;
  const float4* x4 = (const float4*)x;
  #pragma unroll 1
  for (int k4 = 0; k4 < 32; ++k4) {
    const float w0 = W[(size_t)(k4 * 4 + 0) * 128 + col];  // coalesced
    const float w1 = W[(size_t)(k4 * 4 + 1) * 128 + col];
    const float w2 = W[(size_t)(k4 * 4 + 2) * 128 + col];
    const float w3 = W[(size_t)(k4 * 4 + 3) * 128 + col];
    #pragma unroll
    for (int r = 0; r < 16; ++r) {
      const float4 xr = x4[(size_t)(r0 + r) * 32 + k4];    // wave-uniform -> s_load
      acc[r] = fmaf(xr.x, w0, fmaf(xr.y, w1, fmaf(xr.z, w2, fmaf(xr.w, w3, acc[r]))));
    }
  }
  #pragma unroll
  for (int r = 0; r < 16; ++r) O[(size_t)(r0 + r) * 128 + col] = acc[r];
}

// ---------------- edge kernel: lane = one edge (CSR order, dst sorted) ----------------
// waves_per_eu(2,3): cap occupancy at 2-3 waves/EU so the allocator has a
// ~170-256 VGPR budget -> hd[64]+ha[64] stay in registers (no scratch spill).
__global__ __launch_bounds__(256)
__attribute__((amdgpu_waves_per_eu(2, 3)))
void edge_kernel(
    const int* __restrict__ ssrc, const int* __restrict__ sdst,
    const float* __restrict__ pos,
    const float* __restrict__ hbuf, const float* __restrict__ asb, const float* __restrict__ adb,
    const float* __restrict__ Wp1, const float* __restrict__ bp1,
    const float* __restrict__ Wp2, const float* __restrict__ bp2,
    const float* __restrict__ Wa1, const float* __restrict__ ba1,
    const float* __restrict__ Wa2, const float* __restrict__ ba2,
    float* __restrict__ outacc, float* __restrict__ ssum) {
  const int t = blockIdx.x * 256 + threadIdx.x;   // grid exactly covers NE
  const int lane = threadIdx.x & 63;
  const int src = ssrc[t];
  const int dst = sdst[t];

  const float2 pd = ((const float2*)pos)[dst];
  const float2 ps = ((const float2*)pos)[src];
  const float p0 = pd.x - ps.x;
  const float p1 = pd.y - ps.y;

  // segmented-scan predicates over the sorted dst runs in this wave
  bool take[6];
  #pragma unroll
  for (int i = 0; i < 6; ++i) {
    const int off = 1 << i;
    const int dd = __shfl_down(dst, off, 64);
    take[i] = (lane + off < 64) && (dd == dst);
  }
  const int dup = __shfl_up(dst, 1, 64);
  const bool head = (lane == 0) || (dup != dst);

  // pos_nn hidden: hd[k] = relu(p0*Wp1[0][k] + p1*Wp1[1][k] + bp1[k])
  float hd[64];
  #pragma unroll
  for (int k = 0; k < 64; k += 4) {
    const float4 w0 = *(const float4*)(Wp1 + k);
    const float4 w1 = *(const float4*)(Wp1 + 64 + k);
    const float4 bb = *(const float4*)(bp1 + k);
    hd[k + 0] = fmaxf(fmaf(p0, w0.x, fmaf(p1, w1.x, bb.x)), 0.f);
    hd[k + 1] = fmaxf(fmaf(p0, w0.y, fmaf(p1, w1.y, bb.y)), 0.f);
    hd[k + 2] = fmaxf(fmaf(p0, w0.z, fmaf(p1, w1.z, bb.z)), 0.f);
    hd[k + 3] = fmaxf(fmaf(p0, w0.w, fmaf(p1, w1.w, bb.w)), 0.f);
  }

  float ha[64];
  #pragma unroll
  for (int k = 0; k < 64; ++k) ha[k] = 0.f;

  const float4* ad4 = (const float4*)(adb + (size_t)dst * 128);
  const float4* as4 = (const float4*)(asb + (size_t)src * 128);

  // pass 1: delta_c -> u_c -> accumulate attn hidden ha[k]
  #pragma unroll 1
  for (int c4 = 0; c4 < 32; ++c4) {
    const float4 av = ad4[c4];
    const float4 sv = as4[c4];
    const float4 bb = *(const float4*)(bp2 + c4 * 4);
    float d0 = bb.x, d1 = bb.y, d2 = bb.z, d3 = bb.w;
    #pragma unroll
    for (int k = 0; k < 64; ++k) {
      const float4 w = *(const float4*)(Wp2 + k * 128 + c4 * 4);  // uniform -> s_load
      d0 = fmaf(hd[k], w.x, d0);
      d1 = fmaf(hd[k], w.y, d1);
      d2 = fmaf(hd[k], w.z, d2);
      d3 = fmaf(hd[k], w.w, d3);
    }
    float u[4];
    u[0] = av.x - sv.x + fmaxf(d0, 0.f);
    u[1] = av.y - sv.y + fmaxf(d1, 0.f);
    u[2] = av.z - sv.z + fmaxf(d2, 0.f);
    u[3] = av.w - sv.w + fmaxf(d3, 0.f);
    #pragma unroll
    for (int j = 0; j < 4; ++j) {
      const float uj = u[j];
      const float* wa1 = Wa1 + (size_t)(c4 * 4 + j) * 64;
      #pragma unroll
      for (int k = 0; k < 64; k += 4) {
        const float4 w = *(const float4*)(wa1 + k);
        ha[k + 0] = fmaf(uj, w.x, ha[k + 0]);
        ha[k + 1] = fmaf(uj, w.y, ha[k + 1]);
        ha[k + 2] = fmaf(uj, w.z, ha[k + 2]);
        ha[k + 3] = fmaf(uj, w.w, ha[k + 3]);
      }
    }
  }

  #pragma unroll
  for (int k = 0; k < 64; k += 4) {
    const float4 bb = *(const float4*)(ba1 + k);
    ha[k + 0] = fmaxf(ha[k + 0] + bb.x, 0.f);
    ha[k + 1] = fmaxf(ha[k + 1] + bb.y, 0.f);
    ha[k + 2] = fmaxf(ha[k + 2] + bb.z, 0.f);
    ha[k + 3] = fmaxf(ha[k + 3] + bb.w, 0.f);
  }

  const float4* h4 = (const float4*)(hbuf + (size_t)src * 128);
  float* accrow = outacc + (size_t)dst * 128;
  float* srow = ssum + (size_t)dst * 128;

  // pass 2: logits -> e=exp(l) (no max-sub: l>=0, bounded) -> weighted value, reduce, atomics
  #pragma unroll 1
  for (int c4 = 0; c4 < 32; ++c4) {
    const float4 hv = h4[c4];
    const float4 b2 = *(const float4*)(ba2 + c4 * 4);
    const float4 bp = *(const float4*)(bp2 + c4 * 4);
    float l0 = b2.x, l1 = b2.y, l2 = b2.z, l3 = b2.w;
    #pragma unroll
    for (int k = 0; k < 64; ++k) {
      const float4 wa = *(const float4*)(Wa2 + k * 128 + c4 * 4);
      l0 = fmaf(ha[k], wa.x, l0);
      l1 = fmaf(ha[k], wa.y, l1);
      l2 = fmaf(ha[k], wa.z, l2);
      l3 = fmaf(ha[k], wa.w, l3);
    }
    float e0 = bp.x, e1 = bp.y, e2 = bp.z, e3 = bp.w;  // delta recompute
    #pragma unroll
    for (int k = 0; k < 64; ++k) {
      const float4 wp = *(const float4*)(Wp2 + k * 128 + c4 * 4);
      e0 = fmaf(hd[k], wp.x, e0);
      e1 = fmaf(hd[k], wp.y, e1);
      e2 = fmaf(hd[k], wp.z, e2);
      e3 = fmaf(hd[k], wp.w, e3);
    }
    float ee[4], vv[4];
    ee[0] = __expf(fmaxf(l0, 0.f)); vv[0] = ee[0] * (hv.x + fmaxf(e0, 0.f));
    ee[1] = __expf(fmaxf(l1, 0.f)); vv[1] = ee[1] * (hv.y + fmaxf(e1, 0.f));
    ee[2] = __expf(fmaxf(l2, 0.f)); vv[2] = ee[2] * (hv.z + fmaxf(e2, 0.f));
    ee[3] = __expf(fmaxf(l3, 0.f)); vv[3] = ee[3] * (hv.w + fmaxf(e3, 0.f));

    // in-wave segmented suffix-sum over equal-dst runs
    #pragma unroll
    for (int i = 0; i < 6; ++i) {
      const int off = 1 << i;
      #pragma unroll
      for (int j = 0; j < 4; ++j) {
        const float de = __shfl_down(ee[j], off, 64);
        const float dv = __shfl_down(vv[j], off, 64);
        if (take[i]) { ee[j] += de; vv[j] += dv; }
      }
    }
    if (head) {
      #pragma unroll
      for (int j = 0; j < 4; ++j) {
        unsafeAtomicAdd(&srow[c4 * 4 + j], ee[j]);
        unsafeAtomicAdd(&accrow[c4 * 4 + j], vv[j]);
      }
    }
  }
}

// ---------------- finalize: out = relu(acc / (ssum + 1e-16)) ----------------
__global__ __launch_bounds__(256) void finalize_kernel(float4* __restrict__ out4,
                                                       const float4* __restrict__ ssum4) {
  const int i = blockIdx.x * 256 + threadIdx.x;
  const float4 v = out4[i];
  const float4 s = ssum4[i];
  float4 r;
  r.x = fmaxf(v.x / (s.x + 1e-16f), 0.f);
  r.y = fmaxf(v.y / (s.y + 1e-16f), 0.f);
  r.z = fmaxf(v.z / (s.z + 1e-16f), 0.f);
  r.w = fmaxf(v.w / (s.w + 1e-16f), 0.f);
  out4[i] = r;
}

extern "C" void kernel_launch(void* const* d_in, const int* in_sizes, int n_in,
                              void* d_out, int out_size, void* d_ws, size_t ws_size,
                              hipStream_t stream) {
  const float* x     = (const float*)d_in[0];
  const float* pos   = (const float*)d_in[1];
  const int*   ei    = (const int*)d_in[2];
  const float* W_lin = (const float*)d_in[3];
  const float* W_src = (const float*)d_in[4];
  const float* W_dst = (const float*)d_in[5];
  const float* Wp1   = (const float*)d_in[6];
  const float* bp1   = (const float*)d_in[7];
  const float* Wp2   = (const float*)d_in[8];
  const float* bp2   = (const float*)d_in[9];
  const float* Wa1   = (const float*)d_in[10];
  const float* ba1   = (const float*)d_in[11];
  const float* Wa2   = (const float*)d_in[12];
  const float* ba2   = (const float*)d_in[13];
  float* out = (float*)d_out;

  // workspace layout
  float* h    = (float*)d_ws;                      // NN*128
  float* as_  = h   + (size_t)NN * 128;            // NN*128
  float* ad_  = as_ + (size_t)NN * 128;            // NN*128
  float* ssum = ad_ + (size_t)NN * 128;            // NN*128
  int* counts = (int*)(ssum + (size_t)NN * 128);   // NN
  int* ep       = counts + NN;                     // NN
  int* cursor   = ep + NN;                         // NN
  int* blocksum = cursor + NN;                     // 196
  int* blockoff = blocksum + 196;                  // 196
  int* ssrc     = blockoff + 196;                  // NE
  int* sdst     = ssrc + NE;                       // NE

  zero_all<<<6250, 256, 0, stream>>>((float4*)out, (float4*)ssum, (int4*)counts);
  count_kernel<<<3125, 256, 0, stream>>>(ei, counts);
  scan_block<<<196, 256, 0, stream>>>(counts, ep, blocksum);
  scan_tops<<<1, 64, 0, stream>>>(blocksum, blockoff, 196);
  scan_finish<<<196, 256, 0, stream>>>(ep, blockoff, cursor);
  scatter_kernel<<<3125, 256, 0, stream>>>(ei, cursor, ssrc, sdst);
  gemm3_kernel<<<4688, 256, 0, stream>>>(x, W_lin, W_src, W_dst, h, as_, ad_);
  edge_kernel<<<3125, 256, 0, stream>>>(ssrc, sdst, pos, h, as_, ad_,
                                        Wp1, bp1, Wp2, bp2, Wa1, ba1, Wa2, ba2,
                                        out, ssum);
  finalize_kernel<<<6250, 256, 0, stream>>>((float4*)out, (const float4*)ssum);
}